// Round 3
// baseline (261.178 us; speedup 1.0000x reference)
//
#include <hip/hip_runtime.h>

// CubicalModel: Xp = (I @ p).reshape(28,28); dgm1 = Xp[inds1[:,0], inds1[:,1]]
// Only 100 elements of each matvec are gathered -> compute only the 200
// needed row-dot-products (~40 MB HBM read) instead of the full matvecs
// (313.6 MB). Memory-bound floor ~6.5 us at 6.3 TB/s.
//
// R3: single-kernel structure. memset(out)=0 (800 B, graph-capturable), then
// each block atomicAdds its partial into out[o]. Removes the reduce kernel's
// graph node + serialized tail. fp32 atomic order nondeterminism ~1e-5 <<
// 5.6e-2 threshold.

#define P_DIM 50000
#define NV    (P_DIM / 4)      // 12500 float4 per row
#define NGATH 100              // gathered elements per diagram
#define NOUT  200              // total outputs
#define SPLIT 8                // blocks per output row
#define CHUNK ((NV + SPLIT - 1) / SPLIT)  // 1563 float4 per block

__global__ __launch_bounds__(256) void gather_dot_atomic(
    const float* __restrict__ p,
    const float* __restrict__ I,
    const float* __restrict__ J,
    const int*   __restrict__ inds1,
    const int*   __restrict__ inds2,
    float*       __restrict__ out)
{
    const int b = blockIdx.x;       // 0 .. NOUT*SPLIT-1
    const int o = b / SPLIT;        // output index 0..199
    const int s = b % SPLIT;        // segment within the row

    const float* mat;
    const int*   ind;
    int k;
    if (o < NGATH) { mat = I; ind = inds1; k = o; }
    else           { mat = J; ind = inds2; k = o - NGATH; }

    const int r = ind[2 * k];
    const int c = ind[2 * k + 1];
    const size_t flat = (size_t)(r * 28 + c);   // row of the 784 x 50000 matrix

    const float4* __restrict__ row = (const float4*)(mat + flat * (size_t)P_DIM);
    const float4* __restrict__ p4  = (const float4*)p;

    const int start = s * CHUNK;
    const int end   = (start + CHUNK < NV) ? (start + CHUNK) : NV;

    float s0 = 0.f, s1 = 0.f;
    int i = start + (int)threadIdx.x;
    for (; i + 256 < end; i += 512) {
        float4 a0 = row[i];
        float4 p0 = p4[i];
        float4 a1 = row[i + 256];
        float4 p1 = p4[i + 256];
        s0 += a0.x * p0.x + a0.y * p0.y + a0.z * p0.z + a0.w * p0.w;
        s1 += a1.x * p1.x + a1.y * p1.y + a1.z * p1.z + a1.w * p1.w;
    }
    if (i < end) {
        float4 a0 = row[i];
        float4 p0 = p4[i];
        s0 += a0.x * p0.x + a0.y * p0.y + a0.z * p0.z + a0.w * p0.w;
    }
    float sum = s0 + s1;

    // wave(64) shuffle reduction
    #pragma unroll
    for (int off = 32; off > 0; off >>= 1)
        sum += __shfl_down(sum, off, 64);

    __shared__ float smem[4];
    const int lane = threadIdx.x & 63;
    const int wave = threadIdx.x >> 6;
    if (lane == 0) smem[wave] = sum;
    __syncthreads();

    if (threadIdx.x == 0) {
        atomicAdd(&out[o], smem[0] + smem[1] + smem[2] + smem[3]);
    }
}

extern "C" void kernel_launch(void* const* d_in, const int* in_sizes, int n_in,
                              void* d_out, int out_size, void* d_ws, size_t ws_size,
                              hipStream_t stream) {
    const float* p     = (const float*)d_in[0];
    const float* I     = (const float*)d_in[1];
    const float* J     = (const float*)d_in[2];
    const int*   inds1 = (const int*)d_in[3];
    const int*   inds2 = (const int*)d_in[4];
    float* out = (float*)d_out;

    hipMemsetAsync(out, 0, NOUT * sizeof(float), stream);
    gather_dot_atomic<<<NOUT * SPLIT, 256, 0, stream>>>(p, I, J, inds1, inds2, out);
}